// Round 3
// baseline (819.070 us; speedup 1.0000x reference)
//
#include <hip/hip_runtime.h>

#define N_NODES 100000
#define N_HYPER 20000
#define N_EDGES 1600000
#define LDW 136   // LDS row stride in bf16 elems: 272 B = odd*16B (16B-aligned, bank-decorrelated)

typedef unsigned short u16;
typedef unsigned int u32;
typedef short bf16x8 __attribute__((ext_vector_type(8)));
typedef float f32x4 __attribute__((ext_vector_type(4)));
typedef int i32x4 __attribute__((ext_vector_type(4)));

__device__ __forceinline__ f32x4 mfma16(bf16x8 a, bf16x8 b, f32x4 c) {
    return __builtin_amdgcn_mfma_f32_16x16x32_bf16(a, b, c, 0, 0, 0);
}
__device__ __forceinline__ u16 f2bf(float f) {
    unsigned u = __float_as_uint(f);
    unsigned r = u + 0x7FFFu + ((u >> 16) & 1u);   // RN-even
    return (u16)(r >> 16);
}
__device__ __forceinline__ void bfu(unsigned v, float& f0, float& f1) {
    f0 = __uint_as_float(v << 16);
    f1 = __uint_as_float(v & 0xFFFF0000u);
}

// ------- weight prep (bf16, N-major K-contiguous) + h -> bf16 copy ----------
__global__ __launch_bounds__(256) void k_prep(const float* __restrict__ W1, const float* __restrict__ W2,
                                              const float* __restrict__ W3, const float* __restrict__ W4,
                                              u16* __restrict__ W1t, u16* __restrict__ W2t,
                                              u16* __restrict__ W3t, u16* __restrict__ W4t,
                                              const float* __restrict__ h, u16* __restrict__ h_bf) {
    int i = blockIdx.x * 256 + threadIdx.x;
    if (i < 16384) {
        int k = i & 127, n = i >> 7;
        W1t[n * 128 + k] = f2bf(W1[k * 128 + n]);
        W2t[n * 128 + k] = f2bf(W2[k * 128 + n]);
    }
    if (i < 65536) {
        int k = i & 127, n = i >> 7;          // n < 512
        W3t[n * 128 + k] = f2bf(W3[k * 512 + n]);
        int k4 = i & 511, n4 = i >> 9;        // n4 < 128
        W4t[n4 * 512 + k4] = f2bf(W4[k4 * 128 + n4]);
    }
    if (i < 3276800) {                        // 12.8M elems / 4
        float4 v = ((const float4*)h)[i];
        uint2 st;
        st.x = (u32)f2bf(v.x) | ((u32)f2bf(v.y) << 16);
        st.y = (u32)f2bf(v.z) | ((u32)f2bf(v.w) << 16);
        ((uint2*)h_bf)[i] = st;
    }
}

// ------- CSR build: histogram, un-windowed single pass ----------------------
// Device atomics execute fabric-side regardless of XCD (per-XCD L2 is not
// coherent), so windowing bought nothing and cost an 8x edge re-read.
// Each edge is now touched exactly once.
__global__ __launch_bounds__(256) void k_hist(const int* __restrict__ src, const int* __restrict__ dst,
                                              int* __restrict__ cnt_node, int* __restrict__ cnt_he) {
    int stride = gridDim.x * 256;
    const i32x4* s4 = (const i32x4*)src;
    const i32x4* d4 = (const i32x4*)dst;
    for (int q = blockIdx.x * 256 + threadIdx.x; q < N_EDGES / 4; q += stride) {
        i32x4 s = __builtin_nontemporal_load(s4 + q);
        i32x4 d = __builtin_nontemporal_load(d4 + q);
        atomicAdd(&cnt_node[s.x], 1);
        atomicAdd(&cnt_node[s.y], 1);
        atomicAdd(&cnt_node[s.z], 1);
        atomicAdd(&cnt_node[s.w], 1);
        atomicAdd(&cnt_he[d.x], 1);
        atomicAdd(&cnt_he[d.y], 1);
        atomicAdd(&cnt_he[d.z], 1);
        atomicAdd(&cnt_he[d.w], 1);
    }
}

// ------- multi-block scan, phase A: per-block sums --------------------------
// blocks 0..24 -> node array (4096 elems each), blocks 25..29 -> he array
__global__ __launch_bounds__(256) void k_scanA(const int* __restrict__ a_node,
                                               const int* __restrict__ a_he,
                                               int* __restrict__ bs) {
    __shared__ int red[256];
    int b = blockIdx.x;
    const int* a; int base, n;
    if (b < 25) { a = a_node; base = b * 4096; n = N_NODES; }
    else        { a = a_he;   base = (b - 25) * 4096; n = N_HYPER; }
    int t = threadIdx.x;
    int lo = base + t * 16;
    int s = 0;
#pragma unroll
    for (int i = 0; i < 16; ++i) {
        int idx = lo + i;
        if (idx < n) s += a[idx];
    }
    red[t] = s;
    __syncthreads();
    for (int off = 128; off > 0; off >>= 1) {
        if (t < off) red[t] += red[t + off];
        __syncthreads();
    }
    if (t == 0) bs[b] = red[0];
}

// ------- phase B: exclusive scan of the 25+5 block sums ---------------------
__global__ void k_scanB(int* __restrict__ bs) {
    int t = threadIdx.x;
    if (t == 0) {
        int run = 0;
        for (int i = 0; i < 25; ++i) { int v = bs[i]; bs[i] = run; run += v; }
    } else if (t == 1) {
        int run = 0;
        for (int i = 25; i < 30; ++i) { int v = bs[i]; bs[i] = run; run += v; }
    }
}

// ------- phase C: block-local scan + apply base; emit offsets + rsqrt(deg) --
__global__ __launch_bounds__(256) void k_scanC(int* __restrict__ a_node, int* __restrict__ a_he,
                                               float* __restrict__ iq_node, float* __restrict__ iq_he,
                                               const int* __restrict__ bs) {
    __shared__ int pre[256];
    int b = blockIdx.x;
    int* a; float* iq; int base, n;
    if (b < 25) { a = a_node; iq = iq_node; base = b * 4096; n = N_NODES; }
    else        { a = a_he;   iq = iq_he;   base = (b - 25) * 4096; n = N_HYPER; }
    int t = threadIdx.x;
    int lo = base + t * 16;
    int loc = 0;
#pragma unroll
    for (int i = 0; i < 16; ++i) { int idx = lo + i; if (idx < n) loc += a[idx]; }
    pre[t] = loc;
    __syncthreads();
    for (int off = 1; off < 256; off <<= 1) {
        int v = (t >= off) ? pre[t - off] : 0;
        __syncthreads();
        pre[t] += v;
        __syncthreads();
    }
    int running = bs[b] + pre[t] - loc;   // global exclusive prefix for this thread
#pragma unroll
    for (int i = 0; i < 16; ++i) {
        int idx = lo + i;
        if (idx < n) {
            int d = a[idx];
            iq[idx] = rsqrtf((float)(d < 1 ? 1 : d));
            a[idx] = running;
            running += d;
        }
    }
}

// ------- CSR build: fill adjacency, un-windowed single pass -----------------
__global__ __launch_bounds__(256) void k_fill(const int* __restrict__ src, const int* __restrict__ dst,
                                              int* __restrict__ ptr_node, int* __restrict__ ptr_he,
                                              int* __restrict__ adj_node, int* __restrict__ adj_he) {
    int stride = gridDim.x * 256;
    const i32x4* s4 = (const i32x4*)src;
    const i32x4* d4 = (const i32x4*)dst;
    for (int q = blockIdx.x * 256 + threadIdx.x; q < N_EDGES / 4; q += stride) {
        i32x4 s = __builtin_nontemporal_load(s4 + q);
        i32x4 d = __builtin_nontemporal_load(d4 + q);
        int p0 = atomicAdd(&ptr_he[d.x], 1); adj_he[p0] = s.x;
        int p1 = atomicAdd(&ptr_he[d.y], 1); adj_he[p1] = s.y;
        int p2 = atomicAdd(&ptr_he[d.z], 1); adj_he[p2] = s.z;
        int p3 = atomicAdd(&ptr_he[d.w], 1); adj_he[p3] = s.w;
        int p4 = atomicAdd(&ptr_node[s.x], 1); adj_node[p4] = d.x;
        int p5 = atomicAdd(&ptr_node[s.y], 1); adj_node[p5] = d.y;
        int p6 = atomicAdd(&ptr_node[s.z], 1); adj_node[p6] = d.z;
        int p7 = atomicAdd(&ptr_node[s.w], 1); adj_node[p7] = d.w;
    }
}

// ------- gather 1: acc1[d] = sum_{s in adj_he[d]} h_bf[s] * cn[s] -----------
// nt on adj stream (zero reuse) + nt acc1 stores: protect h_bf L2 residency.
__global__ __launch_bounds__(256) void k_gather1(const u16* __restrict__ h_bf,
                                                 const int* __restrict__ adj,
                                                 const int* __restrict__ ptr,
                                                 const float* __restrict__ cn,
                                                 float* __restrict__ acc1) {
    int row = blockIdx.x * 4 + (threadIdx.x >> 6);
    int lane = threadIdx.x & 63;
    int p = lane >> 5, c = lane & 31;
    int start = (row == 0) ? 0 : ptr[row - 1];
    int end = ptr[row];
    const uint2* hp = (const uint2*)h_bf;
    float A0[4] = {0, 0, 0, 0}, A1[4] = {0, 0, 0, 0};
    float f0, f1, f2, f3;
    int j = start;
    for (; j + 3 < end; j += 4) {
        int sA = __builtin_nontemporal_load(adj + j + p);
        int sB = __builtin_nontemporal_load(adj + j + 2 + p);
        float wA = cn[sA], wB = cn[sB];
        uint2 vA = hp[sA * 32 + c];
        uint2 vB = hp[sB * 32 + c];
        bfu(vA.x, f0, f1); bfu(vA.y, f2, f3);
        A0[0] += f0 * wA; A0[1] += f1 * wA; A0[2] += f2 * wA; A0[3] += f3 * wA;
        bfu(vB.x, f0, f1); bfu(vB.y, f2, f3);
        A1[0] += f0 * wB; A1[1] += f1 * wB; A1[2] += f2 * wB; A1[3] += f3 * wB;
    }
    for (; j + 1 < end; j += 2) {
        int sA = __builtin_nontemporal_load(adj + j + p);
        float wA = cn[sA];
        uint2 vA = hp[sA * 32 + c];
        bfu(vA.x, f0, f1); bfu(vA.y, f2, f3);
        A0[0] += f0 * wA; A0[1] += f1 * wA; A0[2] += f2 * wA; A0[3] += f3 * wA;
    }
    if (j < end && p == 0) {
        int sA = __builtin_nontemporal_load(adj + j);
        float wA = cn[sA];
        uint2 vA = hp[sA * 32 + c];
        bfu(vA.x, f0, f1); bfu(vA.y, f2, f3);
        A0[0] += f0 * wA; A0[1] += f1 * wA; A0[2] += f2 * wA; A0[3] += f3 * wA;
    }
    float r0 = A0[0] + A1[0], r1 = A0[1] + A1[1], r2 = A0[2] + A1[2], r3 = A0[3] + A1[3];
    r0 += __shfl_xor(r0, 32, 64);
    r1 += __shfl_xor(r1, 32, 64);
    r2 += __shfl_xor(r2, 32, 64);
    r3 += __shfl_xor(r3, 32, 64);
    if (p == 0) {
        f32x4 o = {r0, r1, r2, r3};
        __builtin_nontemporal_store(o, (f32x4*)acc1 + row * 32 + c);
    }
}

// ------- gather 2: acc2[s] = sum_{d in adj_node[s]} hh2b[d] -----------------
// nt on adj stream + nt acc2 stores (51MB write-allocate would thrash the
// 5.1MB hh2b table we want L2-resident).
__global__ __launch_bounds__(256) void k_gather2(const u16* __restrict__ hh2b,
                                                 const int* __restrict__ adj,
                                                 const int* __restrict__ ptr,
                                                 float* __restrict__ acc2) {
    int row = blockIdx.x * 4 + (threadIdx.x >> 6);
    int lane = threadIdx.x & 63;
    int p = lane >> 5, c = lane & 31;
    int start = (row == 0) ? 0 : ptr[row - 1];
    int end = ptr[row];
    const uint2* hp = (const uint2*)hh2b;
    float A0[4] = {0, 0, 0, 0}, A1[4] = {0, 0, 0, 0};
    float f0, f1, f2, f3;
    int j = start;
    for (; j + 3 < end; j += 4) {
        int dA = __builtin_nontemporal_load(adj + j + p);
        int dB = __builtin_nontemporal_load(adj + j + 2 + p);
        uint2 vA = hp[dA * 32 + c];
        uint2 vB = hp[dB * 32 + c];
        bfu(vA.x, f0, f1); bfu(vA.y, f2, f3);
        A0[0] += f0; A0[1] += f1; A0[2] += f2; A0[3] += f3;
        bfu(vB.x, f0, f1); bfu(vB.y, f2, f3);
        A1[0] += f0; A1[1] += f1; A1[2] += f2; A1[3] += f3;
    }
    for (; j + 1 < end; j += 2) {
        int dA = __builtin_nontemporal_load(adj + j + p);
        uint2 vA = hp[dA * 32 + c];
        bfu(vA.x, f0, f1); bfu(vA.y, f2, f3);
        A0[0] += f0; A0[1] += f1; A0[2] += f2; A0[3] += f3;
    }
    if (j < end && p == 0) {
        int dA = __builtin_nontemporal_load(adj + j);
        uint2 vA = hp[dA * 32 + c];
        bfu(vA.x, f0, f1); bfu(vA.y, f2, f3);
        A0[0] += f0; A0[1] += f1; A0[2] += f2; A0[3] += f3;
    }
    float r0 = A0[0] + A1[0], r1 = A0[1] + A1[1], r2 = A0[2] + A1[2], r3 = A0[3] + A1[3];
    r0 += __shfl_xor(r0, 32, 64);
    r1 += __shfl_xor(r1, 32, 64);
    r2 += __shfl_xor(r2, 32, 64);
    r3 += __shfl_xor(r3, 32, 64);
    if (p == 0) {
        f32x4 o = {r0, r1, r2, r3};
        __builtin_nontemporal_store(o, (f32x4*)acc2 + row * 32 + c);
    }
}

// ------- GEMM1 (MFMA): hh2b = bf16(((acc1*ch) @ W1 + b1) * ch) --------------
__global__ __launch_bounds__(256) void k_gemm1(const float* __restrict__ a, const float* __restrict__ ch,
                                               const u16* __restrict__ W1t,
                                               const float* __restrict__ b1,
                                               u16* __restrict__ hh2b) {
    __shared__ u16 sA[64 * LDW];
    __shared__ u16 sW[128 * LDW];
    int tid = threadIdx.x;
    int r0 = blockIdx.x * 64;
    for (int i = tid; i < 64 * 32; i += 256) {
        int r = i >> 5, c4 = i & 31;
        int row = r0 + r; if (row > N_HYPER - 1) row = N_HYPER - 1;
        float4 v = *(const float4*)(a + row * 128 + c4 * 4);
        float cw = ch[row];
        u16* p = &sA[r * LDW + c4 * 4];
        p[0] = f2bf(v.x * cw); p[1] = f2bf(v.y * cw);
        p[2] = f2bf(v.z * cw); p[3] = f2bf(v.w * cw);
    }
    for (int i = tid; i < 128 * 16; i += 256) {
        int n = i >> 4, c = i & 15;
        *(uint4*)&sW[n * LDW + c * 8] = *(const uint4*)(W1t + n * 128 + c * 8);
    }
    __syncthreads();
    int w = tid >> 6, l15 = tid & 15, quad = (tid & 63) >> 4;
    f32x4 zero = {0.f, 0.f, 0.f, 0.f};
    f32x4 acc[8];
#pragma unroll
    for (int nt = 0; nt < 8; ++nt) acc[nt] = zero;
    int arow = w * 16 + l15;
#pragma unroll
    for (int kt = 0; kt < 4; ++kt) {
        bf16x8 af = *(bf16x8*)&sA[arow * LDW + kt * 32 + quad * 8];
#pragma unroll
        for (int nt = 0; nt < 8; ++nt) {
            bf16x8 bfv = *(bf16x8*)&sW[(nt * 16 + l15) * LDW + kt * 32 + quad * 8];
            acc[nt] = mfma16(af, bfv, acc[nt]);
        }
    }
#pragma unroll
    for (int r = 0; r < 4; ++r) {
        int row = r0 + w * 16 + quad * 4 + r;
        if (row < N_HYPER) {
            float cw = ch[row];
#pragma unroll
            for (int nt = 0; nt < 8; ++nt) {
                int n = nt * 16 + l15;
                hh2b[row * 128 + n] = f2bf((acc[nt][r] + b1[n]) * cw);
            }
        }
    }
}

// --- GEMM2 + residual + LN1 (MFMA, in-place): a := LN(h + (a*cn)@W2 + b2) ---
__global__ __launch_bounds__(256) void k_gemm2_ln(float* a, const float* __restrict__ cn,
                                                  const u16* __restrict__ W2t,
                                                  const float* __restrict__ b2,
                                                  const float* __restrict__ h,
                                                  const float* __restrict__ gamma1,
                                                  const float* __restrict__ beta1) {
    __shared__ u16 sA[64 * LDW];
    __shared__ u16 sW[128 * LDW];
    int tid = threadIdx.x;
    int r0 = blockIdx.x * 64;
    for (int i = tid; i < 64 * 32; i += 256) {
        int r = i >> 5, c4 = i & 31;
        int row = r0 + r; if (row > N_NODES - 1) row = N_NODES - 1;
        float4 v = *(const float4*)(a + row * 128 + c4 * 4);
        float cw = cn[row];
        u16* p = &sA[r * LDW + c4 * 4];
        p[0] = f2bf(v.x * cw); p[1] = f2bf(v.y * cw);
        p[2] = f2bf(v.z * cw); p[3] = f2bf(v.w * cw);
    }
    for (int i = tid; i < 128 * 16; i += 256) {
        int n = i >> 4, c = i & 15;
        *(uint4*)&sW[n * LDW + c * 8] = *(const uint4*)(W2t + n * 128 + c * 8);
    }
    __syncthreads();
    int w = tid >> 6, l15 = tid & 15, quad = (tid & 63) >> 4;
    f32x4 zero = {0.f, 0.f, 0.f, 0.f};
    f32x4 acc[8];
#pragma unroll
    for (int nt = 0; nt < 8; ++nt) acc[nt] = zero;
    int arow = w * 16 + l15;
#pragma unroll
    for (int kt = 0; kt < 4; ++kt) {
        bf16x8 af = *(bf16x8*)&sA[arow * LDW + kt * 32 + quad * 8];
#pragma unroll
        for (int nt = 0; nt < 8; ++nt) {
            bf16x8 bfv = *(bf16x8*)&sW[(nt * 16 + l15) * LDW + kt * 32 + quad * 8];
            acc[nt] = mfma16(af, bfv, acc[nt]);
        }
    }
    float s1[4] = {0, 0, 0, 0}, s2[4] = {0, 0, 0, 0};
#pragma unroll
    for (int r = 0; r < 4; ++r) {
        int row = r0 + w * 16 + quad * 4 + r;
        int rc = row > N_NODES - 1 ? N_NODES - 1 : row;
#pragma unroll
        for (int nt = 0; nt < 8; ++nt) {
            int n = nt * 16 + l15;
            float t = acc[nt][r] + b2[n] + h[rc * 128 + n];
            acc[nt][r] = t;
            s1[r] += t; s2[r] += t * t;
        }
    }
#pragma unroll
    for (int off = 1; off < 16; off <<= 1) {
#pragma unroll
        for (int r = 0; r < 4; ++r) {
            s1[r] += __shfl_xor(s1[r], off, 64);
            s2[r] += __shfl_xor(s2[r], off, 64);
        }
    }
#pragma unroll
    for (int r = 0; r < 4; ++r) {
        int row = r0 + w * 16 + quad * 4 + r;
        if (row < N_NODES) {
            float mu = s1[r] * (1.f / 128.f);
            float var = s2[r] * (1.f / 128.f) - mu * mu;
            float rs = rsqrtf(var + 1e-5f);
#pragma unroll
            for (int nt = 0; nt < 8; ++nt) {
                int n = nt * 16 + l15;
                a[row * 128 + n] = (acc[nt][r] - mu) * rs * gamma1[n] + beta1[n];
            }
        }
    }
}

// ------- FFN + residual + LN2 (MFMA): out = LN(h1 + relu(h1@W3+b3)@W4+b4) ---
__global__ __launch_bounds__(256) void k_ffn_ln(const float* __restrict__ h1,
                                                const u16* __restrict__ W3t,
                                                const float* __restrict__ b3,
                                                const u16* __restrict__ W4t,
                                                const float* __restrict__ b4,
                                                const float* __restrict__ gamma2,
                                                const float* __restrict__ beta2,
                                                float* __restrict__ out) {
    __shared__ u16 sA[64 * LDW];
    __shared__ u16 sW[128 * LDW];
    __shared__ u16 sY[64 * LDW];
    int tid = threadIdx.x;
    int r0 = blockIdx.x * 64;
    for (int i = tid; i < 64 * 32; i += 256) {
        int r = i >> 5, c4 = i & 31;
        int row = r0 + r; if (row > N_NODES - 1) row = N_NODES - 1;
        float4 v = *(const float4*)(h1 + row * 128 + c4 * 4);
        u16* p = &sA[r * LDW + c4 * 4];
        p[0] = f2bf(v.x); p[1] = f2bf(v.y); p[2] = f2bf(v.z); p[3] = f2bf(v.w);
    }
    int w = tid >> 6, l15 = tid & 15, quad = (tid & 63) >> 4;
    int arow = w * 16 + l15;
    f32x4 zero = {0.f, 0.f, 0.f, 0.f};
    f32x4 acc[8];
#pragma unroll
    for (int nt = 0; nt < 8; ++nt) acc[nt] = zero;

    for (int nc = 0; nc < 4; ++nc) {
        __syncthreads();
        for (int i = tid; i < 128 * 16; i += 256) {
            int n = i >> 4, c = i & 15;
            *(uint4*)&sW[n * LDW + c * 8] = *(const uint4*)(W3t + (nc * 128 + n) * 128 + c * 8);
        }
        __syncthreads();
        f32x4 y[8];
#pragma unroll
        for (int nt = 0; nt < 8; ++nt) y[nt] = zero;
#pragma unroll
        for (int kt = 0; kt < 4; ++kt) {
            bf16x8 af = *(bf16x8*)&sA[arow * LDW + kt * 32 + quad * 8];
#pragma unroll
            for (int nt = 0; nt < 8; ++nt) {
                bf16x8 bfv = *(bf16x8*)&sW[(nt * 16 + l15) * LDW + kt * 32 + quad * 8];
                y[nt] = mfma16(af, bfv, y[nt]);
            }
        }
#pragma unroll
        for (int r = 0; r < 4; ++r) {
            int yrow = w * 16 + quad * 4 + r;
#pragma unroll
            for (int nt = 0; nt < 8; ++nt) {
                int n = nt * 16 + l15;
                float vv = y[nt][r] + b3[nc * 128 + n];
                sY[yrow * LDW + n] = f2bf(vv > 0.f ? vv : 0.f);
            }
        }
        __syncthreads();
        for (int i = tid; i < 128 * 16; i += 256) {
            int n = i >> 4, c = i & 15;
            *(uint4*)&sW[n * LDW + c * 8] = *(const uint4*)(W4t + n * 512 + nc * 128 + c * 8);
        }
        __syncthreads();
#pragma unroll
        for (int kt = 0; kt < 4; ++kt) {
            bf16x8 af = *(bf16x8*)&sY[arow * LDW + kt * 32 + quad * 8];
#pragma unroll
            for (int nt = 0; nt < 8; ++nt) {
                bf16x8 bfv = *(bf16x8*)&sW[(nt * 16 + l15) * LDW + kt * 32 + quad * 8];
                acc[nt] = mfma16(af, bfv, acc[nt]);
            }
        }
    }
    float s1[4] = {0, 0, 0, 0}, s2[4] = {0, 0, 0, 0};
#pragma unroll
    for (int r = 0; r < 4; ++r) {
        int row = r0 + w * 16 + quad * 4 + r;
        int rc = row > N_NODES - 1 ? N_NODES - 1 : row;
#pragma unroll
        for (int nt = 0; nt < 8; ++nt) {
            int n = nt * 16 + l15;
            float t = acc[nt][r] + b4[n] + h1[rc * 128 + n];
            acc[nt][r] = t;
            s1[r] += t; s2[r] += t * t;
        }
    }
#pragma unroll
    for (int off = 1; off < 16; off <<= 1) {
#pragma unroll
        for (int r = 0; r < 4; ++r) {
            s1[r] += __shfl_xor(s1[r], off, 64);
            s2[r] += __shfl_xor(s2[r], off, 64);
        }
    }
#pragma unroll
    for (int r = 0; r < 4; ++r) {
        int row = r0 + w * 16 + quad * 4 + r;
        if (row < N_NODES) {
            float mu = s1[r] * (1.f / 128.f);
            float var = s2[r] * (1.f / 128.f) - mu * mu;
            float rs = rsqrtf(var + 1e-5f);
#pragma unroll
            for (int nt = 0; nt < 8; ++nt) {
                int n = nt * 16 + l15;
                out[row * 128 + n] = (acc[nt][r] - mu) * rs * gamma2[n] + beta2[n];
            }
        }
    }
}

extern "C" void kernel_launch(void* const* d_in, const int* in_sizes, int n_in,
                              void* d_out, int out_size, void* d_ws, size_t ws_size,
                              hipStream_t stream) {
    const float* h      = (const float*)d_in[0];
    const int*   src    = (const int*)d_in[1];
    const int*   dst    = (const int*)d_in[2];
    const float* W1     = (const float*)d_in[3];
    const float* b1     = (const float*)d_in[4];
    const float* W2     = (const float*)d_in[5];
    const float* b2     = (const float*)d_in[6];
    const float* W3     = (const float*)d_in[7];
    const float* b3     = (const float*)d_in[8];
    const float* W4     = (const float*)d_in[9];
    const float* b4     = (const float*)d_in[10];
    const float* gamma1 = (const float*)d_in[11];
    const float* beta1  = (const float*)d_in[12];
    const float* gamma2 = (const float*)d_in[13];
    const float* beta2  = (const float*)d_in[14];
    float* out = (float*)d_out;

    // ws layout (bytes), with dead-region aliasing:
    // ptr_node int[100000]     @ 0
    // ptr_he   int[20000]      @ 400000
    // adj_he   int[1.6M]       @ 480000    } hh2b bf16[20000*128] aliases adj_he after gather1
    // adj_node int[1.6M]       @ 6880000
    // cn       f32[100000]     @ 13280000
    // ch       f32[20000]      @ 13680000
    // acc1     f32[20000*128]  @ 13760000  } bs int[30] aliases acc1 during scan phase
    // acc2/h1  f32[100000*128] @ 24000000  } h_bf bf16[100000*128] aliases acc2 until gather2
    // W1t bf16[128*128]        @ 75200000
    // W2t bf16[128*128]        @ 75232768
    // W3t bf16[512*128]        @ 75265536
    // W4t bf16[128*512]        @ 75396608   (end 75527680)
    char* ws = (char*)d_ws;
    int*   ptr_node = (int*)(ws + 0);
    int*   ptr_he   = (int*)(ws + 400000);
    int*   adj_he   = (int*)(ws + 480000);
    int*   adj_node = (int*)(ws + 6880000);
    float* cn       = (float*)(ws + 13280000);
    float* ch       = (float*)(ws + 13680000);
    float* acc1     = (float*)(ws + 13760000);
    float* acc2     = (float*)(ws + 24000000);
    u16*   W1t      = (u16*)(ws + 75200000);
    u16*   W2t      = (u16*)(ws + 75232768);
    u16*   W3t      = (u16*)(ws + 75265536);
    u16*   W4t      = (u16*)(ws + 75396608);
    u16*   h_bf     = (u16*)(ws + 24000000);   // alias acc2 (dead until gather2)
    u16*   hh2b     = (u16*)(ws + 480000);     // alias adj_he (dead after gather1)
    int*   bs       = (int*)(ws + 13760000);   // alias acc1 (dead until gather1)

    hipMemsetAsync(d_ws, 0, 480000, stream);   // zero the two counter arrays only

    k_prep<<<12800, 256, 0, stream>>>(W1, W2, W3, W4, W1t, W2t, W3t, W4t, h, h_bf);
    k_hist<<<1600, 256, 0, stream>>>(src, dst, ptr_node, ptr_he);
    k_scanA<<<30, 256, 0, stream>>>(ptr_node, ptr_he, bs);
    k_scanB<<<1, 64, 0, stream>>>(bs);
    k_scanC<<<30, 256, 0, stream>>>(ptr_node, ptr_he, cn, ch, bs);
    k_fill<<<1600, 256, 0, stream>>>(src, dst, ptr_node, ptr_he, adj_node, adj_he);
    k_gather1<<<5000, 256, 0, stream>>>(h_bf, adj_he, ptr_he, cn, acc1);
    k_gemm1<<<313, 256, 0, stream>>>(acc1, ch, W1t, b1, hh2b);
    k_gather2<<<25000, 256, 0, stream>>>(hh2b, adj_node, ptr_node, acc2);
    k_gemm2_ln<<<1563, 256, 0, stream>>>(acc2, cn, W2t, b2, h, gamma1, beta1);
    k_ffn_ln<<<1563, 256, 0, stream>>>(acc2, W3t, b3, W4t, b4, gamma2, beta2, out);
}

// Round 4
// 517.366 us; speedup vs baseline: 1.5832x; 1.5832x over previous
//
#include <hip/hip_runtime.h>

#define N_NODES 100000
#define N_HYPER 20000
#define N_EDGES 1600000
#define LDW 136   // LDS row stride in bf16 elems: 272 B = odd*16B (16B-aligned, bank-decorrelated)

#define NB_HE 79      // ceil(20000/256) hyperedge buckets (id >> 8)
#define NB_ND 391     // ceil(100000/256) node buckets (id >> 8)
#define CHUNK 6250    // edges per binning block: 256 * 6250 = 1.6M exactly

typedef unsigned short u16;
typedef unsigned int u32;
typedef short bf16x8 __attribute__((ext_vector_type(8)));
typedef float f32x4 __attribute__((ext_vector_type(4)));

__device__ __forceinline__ f32x4 mfma16(bf16x8 a, bf16x8 b, f32x4 c) {
    return __builtin_amdgcn_mfma_f32_16x16x32_bf16(a, b, c, 0, 0, 0);
}
__device__ __forceinline__ u16 f2bf(float f) {
    unsigned u = __float_as_uint(f);
    unsigned r = u + 0x7FFFu + ((u >> 16) & 1u);   // RN-even
    return (u16)(r >> 16);
}
__device__ __forceinline__ void bfu(unsigned v, float& f0, float& f1) {
    f0 = __uint_as_float(v << 16);
    f1 = __uint_as_float(v & 0xFFFF0000u);
}

// ------- weight prep (bf16, N-major K-contiguous) + h -> bf16 copy ----------
__global__ __launch_bounds__(256) void k_prep(const float* __restrict__ W1, const float* __restrict__ W2,
                                              const float* __restrict__ W3, const float* __restrict__ W4,
                                              u16* __restrict__ W1t, u16* __restrict__ W2t,
                                              u16* __restrict__ W3t, u16* __restrict__ W4t,
                                              const float* __restrict__ h, u16* __restrict__ h_bf) {
    int i = blockIdx.x * 256 + threadIdx.x;
    if (i < 16384) {
        int k = i & 127, n = i >> 7;
        W1t[n * 128 + k] = f2bf(W1[k * 128 + n]);
        W2t[n * 128 + k] = f2bf(W2[k * 128 + n]);
    }
    if (i < 65536) {
        int k = i & 127, n = i >> 7;          // n < 512
        W3t[n * 128 + k] = f2bf(W3[k * 512 + n]);
        int k4 = i & 511, n4 = i >> 9;        // n4 < 128
        W4t[n4 * 512 + k4] = f2bf(W4[k4 * 128 + n4]);
    }
    if (i < 3276800) {                        // 12.8M elems / 4
        float4 v = ((const float4*)h)[i];
        uint2 st;
        st.x = (u32)f2bf(v.x) | ((u32)f2bf(v.y) << 16);
        st.y = (u32)f2bf(v.z) | ((u32)f2bf(v.w) << 16);
        ((uint2*)h_bf)[i] = st;
    }
}

// ------- binning phase 1: LDS-privatized bucket histogram -------------------
// 256 blocks x CHUNK edges; one global atomicAdd per (block,bucket):
// 256*470 = 120K atomics instead of 3.2M.
__global__ __launch_bounds__(256) void k_bin_hist(const int* __restrict__ src, const int* __restrict__ dst,
                                                  int* __restrict__ bkt_he, int* __restrict__ bkt_nd) {
    __shared__ int hh[NB_HE], hn[NB_ND];
    int t = threadIdx.x;
    for (int i = t; i < NB_HE; i += 256) hh[i] = 0;
    for (int i = t; i < NB_ND; i += 256) hn[i] = 0;
    __syncthreads();
    int e0 = blockIdx.x * CHUNK;
    for (int e = e0 + t; e < e0 + CHUNK; e += 256) {
        atomicAdd(&hn[src[e] >> 8], 1);
        atomicAdd(&hh[dst[e] >> 8], 1);
    }
    __syncthreads();
    for (int i = t; i < NB_HE; i += 256) if (hh[i]) atomicAdd(&bkt_he[i], hh[i]);
    for (int i = t; i < NB_ND; i += 256) if (hn[i]) atomicAdd(&bkt_nd[i], hn[i]);
}

// ------- binning phase 2: parallel exclusive scan of bucket counts ----------
__global__ __launch_bounds__(512) void k_bin_scan(int* __restrict__ bkt_he, int* __restrict__ bkt_nd,
                                                  int* __restrict__ start_he, int* __restrict__ start_nd,
                                                  int* __restrict__ ptr_node, int* __restrict__ ptr_he) {
    __shared__ int sc[512];
    int t = threadIdx.x;
    int vhe = (t < NB_HE) ? bkt_he[t] : 0;
    sc[t] = vhe; __syncthreads();
    for (int off = 1; off < 512; off <<= 1) {
        int v = (t >= off) ? sc[t - off] : 0; __syncthreads();
        sc[t] += v; __syncthreads();
    }
    if (t < NB_HE) { int ex = sc[t] - vhe; start_he[t] = ex; bkt_he[t] = ex; }
    if (t == NB_HE - 1) start_he[NB_HE] = sc[t];
    __syncthreads();
    int vnd = (t < NB_ND) ? bkt_nd[t] : 0;
    sc[t] = vnd; __syncthreads();
    for (int off = 1; off < 512; off <<= 1) {
        int v = (t >= off) ? sc[t - off] : 0; __syncthreads();
        sc[t] += v; __syncthreads();
    }
    if (t < NB_ND) { int ex = sc[t] - vnd; start_nd[t] = ex; bkt_nd[t] = ex; }
    if (t == NB_ND - 1) start_nd[NB_ND] = sc[t];
    if (t == 0) { ptr_node[N_NODES] = N_EDGES; ptr_he[N_HYPER] = N_EDGES; }
}

// ------- binning phase 3: scatter packed (local_id<<24 | payload) into ------
// per-(block,bucket) reserved runs. Runs are contiguous & written by one
// block in a short time window -> full-line writebacks, no cross-XCD sharing.
__global__ __launch_bounds__(256) void k_bin_fill(const int* __restrict__ src, const int* __restrict__ dst,
                                                  int* __restrict__ bkt_he, int* __restrict__ bkt_nd,
                                                  u32* __restrict__ bin_he, u32* __restrict__ bin_nd) {
    __shared__ int hh[NB_HE], hn[NB_ND], bh[NB_HE], bn[NB_ND];
    int t = threadIdx.x;
    for (int i = t; i < NB_HE; i += 256) hh[i] = 0;
    for (int i = t; i < NB_ND; i += 256) hn[i] = 0;
    __syncthreads();
    int e0 = blockIdx.x * CHUNK;
    for (int e = e0 + t; e < e0 + CHUNK; e += 256) {
        atomicAdd(&hn[src[e] >> 8], 1);
        atomicAdd(&hh[dst[e] >> 8], 1);
    }
    __syncthreads();
    for (int i = t; i < NB_HE; i += 256) { int c = hh[i]; bh[i] = c ? atomicAdd(&bkt_he[i], c) : 0; }
    for (int i = t; i < NB_ND; i += 256) { int c = hn[i]; bn[i] = c ? atomicAdd(&bkt_nd[i], c) : 0; }
    __syncthreads();
    for (int i = t; i < NB_HE; i += 256) hh[i] = 0;
    for (int i = t; i < NB_ND; i += 256) hn[i] = 0;
    __syncthreads();
    for (int e = e0 + t; e < e0 + CHUNK; e += 256) {
        int s = src[e], d = dst[e];
        int bd = d >> 8, bs_ = s >> 8;
        int ph = bh[bd] + atomicAdd(&hh[bd], 1);
        bin_he[ph] = ((u32)(d & 255) << 24) | (u32)s;     // s < 2^17
        int pn = bn[bs_] + atomicAdd(&hn[bs_], 1);
        bin_nd[pn] = ((u32)(s & 255) << 24) | (u32)d;     // d < 2^15
    }
}

// ------- degrees from binned data (replaces global-atomic histogram) --------
// bucket-per-block: LDS count of 256 local ids, dense degree writes.
__global__ __launch_bounds__(256) void k_deg(const u32* __restrict__ bin_he, const u32* __restrict__ bin_nd,
                                             const int* __restrict__ start_he, const int* __restrict__ start_nd,
                                             int* __restrict__ deg_nd, int* __restrict__ deg_he) {
    __shared__ int cnt[256];
    int t = threadIdx.x, b = blockIdx.x;
    cnt[t] = 0; __syncthreads();
    if (b < NB_HE) {
        int lo = start_he[b], hi = start_he[b + 1];
        for (int j = lo + t; j < hi; j += 256) atomicAdd(&cnt[bin_he[j] >> 24], 1);
        __syncthreads();
        int id = b * 256 + t;
        if (id < N_HYPER) deg_he[id] = cnt[t];
    } else {
        int bb = b - NB_HE;
        int lo = start_nd[bb], hi = start_nd[bb + 1];
        for (int j = lo + t; j < hi; j += 256) atomicAdd(&cnt[bin_nd[j] >> 24], 1);
        __syncthreads();
        int id = bb * 256 + t;
        if (id < N_NODES) deg_nd[id] = cnt[t];
    }
}

// ------- multi-block scan, phase A: per-block sums --------------------------
// blocks 0..24 -> node array (4096 elems each), blocks 25..29 -> he array
__global__ __launch_bounds__(256) void k_scanA(const int* __restrict__ a_node,
                                               const int* __restrict__ a_he,
                                               int* __restrict__ bs) {
    __shared__ int red[256];
    int b = blockIdx.x;
    const int* a; int base, n;
    if (b < 25) { a = a_node; base = b * 4096; n = N_NODES; }
    else        { a = a_he;   base = (b - 25) * 4096; n = N_HYPER; }
    int t = threadIdx.x;
    int lo = base + t * 16;
    int s = 0;
#pragma unroll
    for (int i = 0; i < 16; ++i) {
        int idx = lo + i;
        if (idx < n) s += a[idx];
    }
    red[t] = s;
    __syncthreads();
    for (int off = 128; off > 0; off >>= 1) {
        if (t < off) red[t] += red[t + off];
        __syncthreads();
    }
    if (t == 0) bs[b] = red[0];
}

// ------- phase B: exclusive scan of the 25+5 block sums ---------------------
__global__ void k_scanB(int* __restrict__ bs) {
    int t = threadIdx.x;
    if (t == 0) {
        int run = 0;
        for (int i = 0; i < 25; ++i) { int v = bs[i]; bs[i] = run; run += v; }
    } else if (t == 1) {
        int run = 0;
        for (int i = 25; i < 30; ++i) { int v = bs[i]; bs[i] = run; run += v; }
    }
}

// ------- phase C: block-local scan + apply base; emit CSR starts + rsqrt ----
__global__ __launch_bounds__(256) void k_scanC(int* __restrict__ a_node, int* __restrict__ a_he,
                                               float* __restrict__ iq_node, float* __restrict__ iq_he,
                                               const int* __restrict__ bs) {
    __shared__ int pre[256];
    int b = blockIdx.x;
    int* a; float* iq; int base, n;
    if (b < 25) { a = a_node; iq = iq_node; base = b * 4096; n = N_NODES; }
    else        { a = a_he;   iq = iq_he;   base = (b - 25) * 4096; n = N_HYPER; }
    int t = threadIdx.x;
    int lo = base + t * 16;
    int loc = 0;
#pragma unroll
    for (int i = 0; i < 16; ++i) { int idx = lo + i; if (idx < n) loc += a[idx]; }
    pre[t] = loc;
    __syncthreads();
    for (int off = 1; off < 256; off <<= 1) {
        int v = (t >= off) ? pre[t - off] : 0;
        __syncthreads();
        pre[t] += v;
        __syncthreads();
    }
    int running = bs[b] + pre[t] - loc;   // global exclusive prefix for this thread
#pragma unroll
    for (int i = 0; i < 16; ++i) {
        int idx = lo + i;
        if (idx < n) {
            int d = a[idx];
            iq[idx] = rsqrtf((float)(d < 1 ? 1 : d));
            a[idx] = running;             // CSR segment START (sentinel set in k_bin_scan)
            running += d;
        }
    }
}

// ------- final CSR fill from bins: bucket-per-block, LDS base+rank ----------
// All writes for a bucket come from ONE block into one compact region.
__global__ __launch_bounds__(256) void k_fill2(const u32* __restrict__ bin_he, const u32* __restrict__ bin_nd,
                                               const int* __restrict__ start_he, const int* __restrict__ start_nd,
                                               const int* __restrict__ ptr_he, const int* __restrict__ ptr_node,
                                               int* __restrict__ adj_he, int* __restrict__ adj_node) {
    __shared__ int base[256], rk[256];
    int t = threadIdx.x, b = blockIdx.x;
    rk[t] = 0;
    if (b < NB_HE) {
        int id = b * 256 + t;
        base[t] = (id < N_HYPER) ? ptr_he[id] : 0;
        __syncthreads();
        int lo = start_he[b], hi = start_he[b + 1];
        for (int j = lo + t; j < hi; j += 256) {
            u32 v = bin_he[j];
            int lid = v >> 24;
            int pos = base[lid] + atomicAdd(&rk[lid], 1);
            adj_he[pos] = (int)(v & 0xFFFFFFu);
        }
    } else {
        int bb = b - NB_HE;
        int id = bb * 256 + t;
        base[t] = (id < N_NODES) ? ptr_node[id] : 0;
        __syncthreads();
        int lo = start_nd[bb], hi = start_nd[bb + 1];
        for (int j = lo + t; j < hi; j += 256) {
            u32 v = bin_nd[j];
            int lid = v >> 24;
            int pos = base[lid] + atomicAdd(&rk[lid], 1);
            adj_node[pos] = (int)(v & 0xFFFFFFu);
        }
    }
}

// ------- gather 1: acc1[d] = sum_{s in adj_he[d]} h_bf[s] * cn[s] -----------
__global__ __launch_bounds__(256) void k_gather1(const u16* __restrict__ h_bf,
                                                 const int* __restrict__ adj,
                                                 const int* __restrict__ ptr,
                                                 const float* __restrict__ cn,
                                                 float* __restrict__ acc1) {
    int row = blockIdx.x * 4 + (threadIdx.x >> 6);
    int lane = threadIdx.x & 63;
    int p = lane >> 5, c = lane & 31;
    int start = ptr[row];
    int end = ptr[row + 1];
    const uint2* hp = (const uint2*)h_bf;
    float A0[4] = {0, 0, 0, 0}, A1[4] = {0, 0, 0, 0};
    float f0, f1, f2, f3;
    int j = start;
    for (; j + 3 < end; j += 4) {
        int sA = adj[j + p], sB = adj[j + 2 + p];
        float wA = cn[sA], wB = cn[sB];
        uint2 vA = hp[sA * 32 + c];
        uint2 vB = hp[sB * 32 + c];
        bfu(vA.x, f0, f1); bfu(vA.y, f2, f3);
        A0[0] += f0 * wA; A0[1] += f1 * wA; A0[2] += f2 * wA; A0[3] += f3 * wA;
        bfu(vB.x, f0, f1); bfu(vB.y, f2, f3);
        A1[0] += f0 * wB; A1[1] += f1 * wB; A1[2] += f2 * wB; A1[3] += f3 * wB;
    }
    for (; j + 1 < end; j += 2) {
        int sA = adj[j + p];
        float wA = cn[sA];
        uint2 vA = hp[sA * 32 + c];
        bfu(vA.x, f0, f1); bfu(vA.y, f2, f3);
        A0[0] += f0 * wA; A0[1] += f1 * wA; A0[2] += f2 * wA; A0[3] += f3 * wA;
    }
    if (j < end && p == 0) {
        int sA = adj[j];
        float wA = cn[sA];
        uint2 vA = hp[sA * 32 + c];
        bfu(vA.x, f0, f1); bfu(vA.y, f2, f3);
        A0[0] += f0 * wA; A0[1] += f1 * wA; A0[2] += f2 * wA; A0[3] += f3 * wA;
    }
    float r0 = A0[0] + A1[0], r1 = A0[1] + A1[1], r2 = A0[2] + A1[2], r3 = A0[3] + A1[3];
    r0 += __shfl_xor(r0, 32, 64);
    r1 += __shfl_xor(r1, 32, 64);
    r2 += __shfl_xor(r2, 32, 64);
    r3 += __shfl_xor(r3, 32, 64);
    if (p == 0) {
        float4 o; o.x = r0; o.y = r1; o.z = r2; o.w = r3;
        ((float4*)acc1)[row * 32 + c] = o;
    }
}

// ------- gather 2: acc2[s] = sum_{d in adj_node[s]} hh2b[d] -----------------
__global__ __launch_bounds__(256) void k_gather2(const u16* __restrict__ hh2b,
                                                 const int* __restrict__ adj,
                                                 const int* __restrict__ ptr,
                                                 float* __restrict__ acc2) {
    int row = blockIdx.x * 4 + (threadIdx.x >> 6);
    int lane = threadIdx.x & 63;
    int p = lane >> 5, c = lane & 31;
    int start = ptr[row];
    int end = ptr[row + 1];
    const uint2* hp = (const uint2*)hh2b;
    float A0[4] = {0, 0, 0, 0}, A1[4] = {0, 0, 0, 0};
    float f0, f1, f2, f3;
    int j = start;
    for (; j + 3 < end; j += 4) {
        int dA = adj[j + p], dB = adj[j + 2 + p];
        uint2 vA = hp[dA * 32 + c];
        uint2 vB = hp[dB * 32 + c];
        bfu(vA.x, f0, f1); bfu(vA.y, f2, f3);
        A0[0] += f0; A0[1] += f1; A0[2] += f2; A0[3] += f3;
        bfu(vB.x, f0, f1); bfu(vB.y, f2, f3);
        A1[0] += f0; A1[1] += f1; A1[2] += f2; A1[3] += f3;
    }
    for (; j + 1 < end; j += 2) {
        int dA = adj[j + p];
        uint2 vA = hp[dA * 32 + c];
        bfu(vA.x, f0, f1); bfu(vA.y, f2, f3);
        A0[0] += f0; A0[1] += f1; A0[2] += f2; A0[3] += f3;
    }
    if (j < end && p == 0) {
        int dA = adj[j];
        uint2 vA = hp[dA * 32 + c];
        bfu(vA.x, f0, f1); bfu(vA.y, f2, f3);
        A0[0] += f0; A0[1] += f1; A0[2] += f2; A0[3] += f3;
    }
    float r0 = A0[0] + A1[0], r1 = A0[1] + A1[1], r2 = A0[2] + A1[2], r3 = A0[3] + A1[3];
    r0 += __shfl_xor(r0, 32, 64);
    r1 += __shfl_xor(r1, 32, 64);
    r2 += __shfl_xor(r2, 32, 64);
    r3 += __shfl_xor(r3, 32, 64);
    if (p == 0) {
        float4 o; o.x = r0; o.y = r1; o.z = r2; o.w = r3;
        ((float4*)acc2)[row * 32 + c] = o;
    }
}

// ------- GEMM1 (MFMA): hh2b = bf16(((acc1*ch) @ W1 + b1) * ch) --------------
__global__ __launch_bounds__(256) void k_gemm1(const float* __restrict__ a, const float* __restrict__ ch,
                                               const u16* __restrict__ W1t,
                                               const float* __restrict__ b1,
                                               u16* __restrict__ hh2b) {
    __shared__ u16 sA[64 * LDW];
    __shared__ u16 sW[128 * LDW];
    int tid = threadIdx.x;
    int r0 = blockIdx.x * 64;
    for (int i = tid; i < 64 * 32; i += 256) {
        int r = i >> 5, c4 = i & 31;
        int row = r0 + r; if (row > N_HYPER - 1) row = N_HYPER - 1;
        float4 v = *(const float4*)(a + row * 128 + c4 * 4);
        float cw = ch[row];
        u16* p = &sA[r * LDW + c4 * 4];
        p[0] = f2bf(v.x * cw); p[1] = f2bf(v.y * cw);
        p[2] = f2bf(v.z * cw); p[3] = f2bf(v.w * cw);
    }
    for (int i = tid; i < 128 * 16; i += 256) {
        int n = i >> 4, c = i & 15;
        *(uint4*)&sW[n * LDW + c * 8] = *(const uint4*)(W1t + n * 128 + c * 8);
    }
    __syncthreads();
    int w = tid >> 6, l15 = tid & 15, quad = (tid & 63) >> 4;
    f32x4 zero = {0.f, 0.f, 0.f, 0.f};
    f32x4 acc[8];
#pragma unroll
    for (int nt = 0; nt < 8; ++nt) acc[nt] = zero;
    int arow = w * 16 + l15;
#pragma unroll
    for (int kt = 0; kt < 4; ++kt) {
        bf16x8 af = *(bf16x8*)&sA[arow * LDW + kt * 32 + quad * 8];
#pragma unroll
        for (int nt = 0; nt < 8; ++nt) {
            bf16x8 bfv = *(bf16x8*)&sW[(nt * 16 + l15) * LDW + kt * 32 + quad * 8];
            acc[nt] = mfma16(af, bfv, acc[nt]);
        }
    }
#pragma unroll
    for (int r = 0; r < 4; ++r) {
        int row = r0 + w * 16 + quad * 4 + r;
        if (row < N_HYPER) {
            float cw = ch[row];
#pragma unroll
            for (int nt = 0; nt < 8; ++nt) {
                int n = nt * 16 + l15;
                hh2b[row * 128 + n] = f2bf((acc[nt][r] + b1[n]) * cw);
            }
        }
    }
}

// --- GEMM2 + residual + LN1 (MFMA, in-place): a := LN(h + (a*cn)@W2 + b2) ---
__global__ __launch_bounds__(256) void k_gemm2_ln(float* a, const float* __restrict__ cn,
                                                  const u16* __restrict__ W2t,
                                                  const float* __restrict__ b2,
                                                  const float* __restrict__ h,
                                                  const float* __restrict__ gamma1,
                                                  const float* __restrict__ beta1) {
    __shared__ u16 sA[64 * LDW];
    __shared__ u16 sW[128 * LDW];
    int tid = threadIdx.x;
    int r0 = blockIdx.x * 64;
    for (int i = tid; i < 64 * 32; i += 256) {
        int r = i >> 5, c4 = i & 31;
        int row = r0 + r; if (row > N_NODES - 1) row = N_NODES - 1;
        float4 v = *(const float4*)(a + row * 128 + c4 * 4);
        float cw = cn[row];
        u16* p = &sA[r * LDW + c4 * 4];
        p[0] = f2bf(v.x * cw); p[1] = f2bf(v.y * cw);
        p[2] = f2bf(v.z * cw); p[3] = f2bf(v.w * cw);
    }
    for (int i = tid; i < 128 * 16; i += 256) {
        int n = i >> 4, c = i & 15;
        *(uint4*)&sW[n * LDW + c * 8] = *(const uint4*)(W2t + n * 128 + c * 8);
    }
    __syncthreads();
    int w = tid >> 6, l15 = tid & 15, quad = (tid & 63) >> 4;
    f32x4 zero = {0.f, 0.f, 0.f, 0.f};
    f32x4 acc[8];
#pragma unroll
    for (int nt = 0; nt < 8; ++nt) acc[nt] = zero;
    int arow = w * 16 + l15;
#pragma unroll
    for (int kt = 0; kt < 4; ++kt) {
        bf16x8 af = *(bf16x8*)&sA[arow * LDW + kt * 32 + quad * 8];
#pragma unroll
        for (int nt = 0; nt < 8; ++nt) {
            bf16x8 bfv = *(bf16x8*)&sW[(nt * 16 + l15) * LDW + kt * 32 + quad * 8];
            acc[nt] = mfma16(af, bfv, acc[nt]);
        }
    }
    float s1[4] = {0, 0, 0, 0}, s2[4] = {0, 0, 0, 0};
#pragma unroll
    for (int r = 0; r < 4; ++r) {
        int row = r0 + w * 16 + quad * 4 + r;
        int rc = row > N_NODES - 1 ? N_NODES - 1 : row;
#pragma unroll
        for (int nt = 0; nt < 8; ++nt) {
            int n = nt * 16 + l15;
            float t = acc[nt][r] + b2[n] + h[rc * 128 + n];
            acc[nt][r] = t;
            s1[r] += t; s2[r] += t * t;
        }
    }
#pragma unroll
    for (int off = 1; off < 16; off <<= 1) {
#pragma unroll
        for (int r = 0; r < 4; ++r) {
            s1[r] += __shfl_xor(s1[r], off, 64);
            s2[r] += __shfl_xor(s2[r], off, 64);
        }
    }
#pragma unroll
    for (int r = 0; r < 4; ++r) {
        int row = r0 + w * 16 + quad * 4 + r;
        if (row < N_NODES) {
            float mu = s1[r] * (1.f / 128.f);
            float var = s2[r] * (1.f / 128.f) - mu * mu;
            float rs = rsqrtf(var + 1e-5f);
#pragma unroll
            for (int nt = 0; nt < 8; ++nt) {
                int n = nt * 16 + l15;
                a[row * 128 + n] = (acc[nt][r] - mu) * rs * gamma1[n] + beta1[n];
            }
        }
    }
}

// ------- FFN + residual + LN2 (MFMA): out = LN(h1 + relu(h1@W3+b3)@W4+b4) ---
__global__ __launch_bounds__(256) void k_ffn_ln(const float* __restrict__ h1,
                                                const u16* __restrict__ W3t,
                                                const float* __restrict__ b3,
                                                const u16* __restrict__ W4t,
                                                const float* __restrict__ b4,
                                                const float* __restrict__ gamma2,
                                                const float* __restrict__ beta2,
                                                float* __restrict__ out) {
    __shared__ u16 sA[64 * LDW];
    __shared__ u16 sW[128 * LDW];
    __shared__ u16 sY[64 * LDW];
    int tid = threadIdx.x;
    int r0 = blockIdx.x * 64;
    for (int i = tid; i < 64 * 32; i += 256) {
        int r = i >> 5, c4 = i & 31;
        int row = r0 + r; if (row > N_NODES - 1) row = N_NODES - 1;
        float4 v = *(const float4*)(h1 + row * 128 + c4 * 4);
        u16* p = &sA[r * LDW + c4 * 4];
        p[0] = f2bf(v.x); p[1] = f2bf(v.y); p[2] = f2bf(v.z); p[3] = f2bf(v.w);
    }
    int w = tid >> 6, l15 = tid & 15, quad = (tid & 63) >> 4;
    int arow = w * 16 + l15;
    f32x4 zero = {0.f, 0.f, 0.f, 0.f};
    f32x4 acc[8];
#pragma unroll
    for (int nt = 0; nt < 8; ++nt) acc[nt] = zero;

    for (int nc = 0; nc < 4; ++nc) {
        __syncthreads();
        for (int i = tid; i < 128 * 16; i += 256) {
            int n = i >> 4, c = i & 15;
            *(uint4*)&sW[n * LDW + c * 8] = *(const uint4*)(W3t + (nc * 128 + n) * 128 + c * 8);
        }
        __syncthreads();
        f32x4 y[8];
#pragma unroll
        for (int nt = 0; nt < 8; ++nt) y[nt] = zero;
#pragma unroll
        for (int kt = 0; kt < 4; ++kt) {
            bf16x8 af = *(bf16x8*)&sA[arow * LDW + kt * 32 + quad * 8];
#pragma unroll
            for (int nt = 0; nt < 8; ++nt) {
                bf16x8 bfv = *(bf16x8*)&sW[(nt * 16 + l15) * LDW + kt * 32 + quad * 8];
                y[nt] = mfma16(af, bfv, y[nt]);
            }
        }
#pragma unroll
        for (int r = 0; r < 4; ++r) {
            int yrow = w * 16 + quad * 4 + r;
#pragma unroll
            for (int nt = 0; nt < 8; ++nt) {
                int n = nt * 16 + l15;
                float vv = y[nt][r] + b3[nc * 128 + n];
                sY[yrow * LDW + n] = f2bf(vv > 0.f ? vv : 0.f);
            }
        }
        __syncthreads();
        for (int i = tid; i < 128 * 16; i += 256) {
            int n = i >> 4, c = i & 15;
            *(uint4*)&sW[n * LDW + c * 8] = *(const uint4*)(W4t + n * 512 + nc * 128 + c * 8);
        }
        __syncthreads();
#pragma unroll
        for (int kt = 0; kt < 4; ++kt) {
            bf16x8 af = *(bf16x8*)&sY[arow * LDW + kt * 32 + quad * 8];
#pragma unroll
            for (int nt = 0; nt < 8; ++nt) {
                bf16x8 bfv = *(bf16x8*)&sW[(nt * 16 + l15) * LDW + kt * 32 + quad * 8];
                acc[nt] = mfma16(af, bfv, acc[nt]);
            }
        }
    }
    float s1[4] = {0, 0, 0, 0}, s2[4] = {0, 0, 0, 0};
#pragma unroll
    for (int r = 0; r < 4; ++r) {
        int row = r0 + w * 16 + quad * 4 + r;
        int rc = row > N_NODES - 1 ? N_NODES - 1 : row;
#pragma unroll
        for (int nt = 0; nt < 8; ++nt) {
            int n = nt * 16 + l15;
            float t = acc[nt][r] + b4[n] + h1[rc * 128 + n];
            acc[nt][r] = t;
            s1[r] += t; s2[r] += t * t;
        }
    }
#pragma unroll
    for (int off = 1; off < 16; off <<= 1) {
#pragma unroll
        for (int r = 0; r < 4; ++r) {
            s1[r] += __shfl_xor(s1[r], off, 64);
            s2[r] += __shfl_xor(s2[r], off, 64);
        }
    }
#pragma unroll
    for (int r = 0; r < 4; ++r) {
        int row = r0 + w * 16 + quad * 4 + r;
        if (row < N_NODES) {
            float mu = s1[r] * (1.f / 128.f);
            float var = s2[r] * (1.f / 128.f) - mu * mu;
            float rs = rsqrtf(var + 1e-5f);
#pragma unroll
            for (int nt = 0; nt < 8; ++nt) {
                int n = nt * 16 + l15;
                out[row * 128 + n] = (acc[nt][r] - mu) * rs * gamma2[n] + beta2[n];
            }
        }
    }
}

extern "C" void kernel_launch(void* const* d_in, const int* in_sizes, int n_in,
                              void* d_out, int out_size, void* d_ws, size_t ws_size,
                              hipStream_t stream) {
    const float* h      = (const float*)d_in[0];
    const int*   src    = (const int*)d_in[1];
    const int*   dst    = (const int*)d_in[2];
    const float* W1     = (const float*)d_in[3];
    const float* b1     = (const float*)d_in[4];
    const float* W2     = (const float*)d_in[5];
    const float* b2     = (const float*)d_in[6];
    const float* W3     = (const float*)d_in[7];
    const float* b3     = (const float*)d_in[8];
    const float* W4     = (const float*)d_in[9];
    const float* b4     = (const float*)d_in[10];
    const float* gamma1 = (const float*)d_in[11];
    const float* beta1  = (const float*)d_in[12];
    const float* gamma2 = (const float*)d_in[13];
    const float* beta2  = (const float*)d_in[14];
    float* out = (float*)d_out;

    // ws layout (bytes), with dead-region aliasing:
    // ptr_node int[100001]     @ 0         (CSR starts + sentinel; counts during scan)
    // ptr_he   int[20001]      @ 400512
    // adj_he   int[1.6M]       @ 481280    } hh2b bf16[20000*128] aliases after gather1
    // adj_node int[1.6M]       @ 6881280
    // cn       f32[100000]     @ 13281280
    // ch       f32[20000]      @ 13681280
    // h_bf     bf16[100000*128]@ 24000000  } head of acc2 span (dead by gather2)
    // bin_he   u32[1.6M]       @ 49600000  } inside acc2 span (dead by gather2)
    // bin_nd   u32[1.6M]       @ 56000000  }
    // acc1     f32[20000*128]  @ 62400000  } inside acc2 span (dead by gather2)
    // bkt_he[80]/bkt_nd[392]   @ 72640000  (zeroed; reservation counters)
    // start_he[80]/start_nd[392] @ 72642560
    // bs int[30]               @ 72644864
    // acc2/h1  f32[100000*128] @ 24000000 .. 75200000 (written at gather2)
    // W1t/W2t/W3t/W4t          @ 75200000 .. 75527680
    char* ws = (char*)d_ws;
    int*   ptr_node = (int*)(ws + 0);
    int*   ptr_he   = (int*)(ws + 400512);
    int*   adj_he   = (int*)(ws + 481280);
    int*   adj_node = (int*)(ws + 6881280);
    float* cn       = (float*)(ws + 13281280);
    float* ch       = (float*)(ws + 13681280);
    u16*   h_bf     = (u16*)(ws + 24000000);
    u32*   bin_he   = (u32*)(ws + 49600000);
    u32*   bin_nd   = (u32*)(ws + 56000000);
    float* acc1     = (float*)(ws + 62400000);
    int*   bkt_he   = (int*)(ws + 72640000);
    int*   bkt_nd   = (int*)(ws + 72640512);
    int*   start_he = (int*)(ws + 72642560);
    int*   start_nd = (int*)(ws + 72643072);
    int*   bs       = (int*)(ws + 72644864);
    float* acc2     = (float*)(ws + 24000000);
    u16*   hh2b     = (u16*)(ws + 481280);     // alias adj_he (dead after gather1)
    u16*   W1t      = (u16*)(ws + 75200000);
    u16*   W2t      = (u16*)(ws + 75232768);
    u16*   W3t      = (u16*)(ws + 75265536);
    u16*   W4t      = (u16*)(ws + 75396608);

    hipMemsetAsync(ws + 72640000, 0, 2560, stream);   // zero bucket counters only

    k_prep<<<12800, 256, 0, stream>>>(W1, W2, W3, W4, W1t, W2t, W3t, W4t, h, h_bf);
    k_bin_hist<<<256, 256, 0, stream>>>(src, dst, bkt_he, bkt_nd);
    k_bin_scan<<<1, 512, 0, stream>>>(bkt_he, bkt_nd, start_he, start_nd, ptr_node, ptr_he);
    k_bin_fill<<<256, 256, 0, stream>>>(src, dst, bkt_he, bkt_nd, bin_he, bin_nd);
    k_deg<<<NB_HE + NB_ND, 256, 0, stream>>>(bin_he, bin_nd, start_he, start_nd, ptr_node, ptr_he);
    k_scanA<<<30, 256, 0, stream>>>(ptr_node, ptr_he, bs);
    k_scanB<<<1, 64, 0, stream>>>(bs);
    k_scanC<<<30, 256, 0, stream>>>(ptr_node, ptr_he, cn, ch, bs);
    k_fill2<<<NB_HE + NB_ND, 256, 0, stream>>>(bin_he, bin_nd, start_he, start_nd,
                                               ptr_he, ptr_node, adj_he, adj_node);
    k_gather1<<<5000, 256, 0, stream>>>(h_bf, adj_he, ptr_he, cn, acc1);
    k_gemm1<<<313, 256, 0, stream>>>(acc1, ch, W1t, b1, hh2b);
    k_gather2<<<25000, 256, 0, stream>>>(hh2b, adj_node, ptr_node, acc2);
    k_gemm2_ln<<<1563, 256, 0, stream>>>(acc2, cn, W2t, b2, h, gamma1, beta1);
    k_ffn_ln<<<1563, 256, 0, stream>>>(acc2, W3t, b3, W4t, b4, gamma2, beta2, out);
}